// Round 10
// baseline (741.772 us; speedup 1.0000x reference)
//
#include <hip/hip_runtime.h>
#include <cstdint>

typedef _Float16 f16;
typedef __attribute__((ext_vector_type(8))) _Float16 f16x8;
typedef __attribute__((ext_vector_type(4))) _Float16 f16x4;
typedef __attribute__((ext_vector_type(4))) float f32x4;

typedef __attribute__((address_space(1))) void gvoid_t;
typedef __attribute__((address_space(3))) void lvoid_t;

// async global->LDS, 16B per lane. LDS dest wave-uniform base; HW adds lane*16.
__device__ __forceinline__ void async_copy16(void* lds, const void* g) {
  __builtin_amdgcn_global_load_lds((gvoid_t*)(uintptr_t)g, (lvoid_t*)lds, 16, 0, 0);
}

#define BARRIER()   __builtin_amdgcn_s_barrier()
#define SCHEDBAR()  __builtin_amdgcn_sched_barrier(0)
#define VMCNT(n)    do { SCHEDBAR(); asm volatile("s_waitcnt vmcnt(" #n ")"); SCHEDBAR(); } while (0)

#define MFMA16(a, b, c) __builtin_amdgcn_mfma_f32_16x16x32_f16((a), (b), (c), 0, 0, 0)

struct RCtx {
  int sdst, rA, rB, cb0, cb1, lda, ldb;
  const f16 *gAa, *gAb, *gBa, *gBb;   // staging sources (row r0, preswizzled col)
};

#define CLUSTER(AF, BF, Q) { \
    __builtin_amdgcn_s_setprio(1); \
    _Pragma("unroll") \
    for (int n = 0; n < 4; ++n) { \
      _Pragma("unroll") \
      for (int i = 0; i < 4; ++i) \
        acc[(Q)*4 + i][n] = MFMA16(AF[i], BF[n], acc[(Q)*4 + i][n]); \
    } \
    __builtin_amdgcn_s_setprio(0); }

// One K-tile (K=64), 4 phases {reads; 2 gloads; [vmcnt]; barrier; 16 MFMA}.
// Reads balanced 8/8/4/4 via kk-split: ph0 A(m0-3,kk0)+B(kk0); ph1 A(m4-7,kk0)
// +B(kk1); ph2 A(m0-3,kk1); ph3 A(m4-7,kk1).  Stages: s0=B(t+1)b, s1=A(t+2)a,
// s2=A(t+2)b, s3=B(t+2)a.  W=1 -> vmcnt(6) (A(t+2)a,b + B(t+2)a stay in
// flight), W=2 -> vmcnt(0), W=0 -> none.
template<int W>
__device__ __forceinline__ void tile4(const f16* mA, const f16* mB,
    f16* s0, long k0, f16* s1, f16* s2, long kA, f16* s3, long kB,
    const RCtx& c, f32x4 (&acc)[8][4])
{
  f16x8 af[4], bf[4], bf2[4];
  // ---- ph0 ----
#pragma unroll
  for (int i = 0; i < 4; ++i) af[i] = *(const f16x8*)&mA[c.rA + i * 1024 + c.cb0];
#pragma unroll
  for (int n = 0; n < 4; ++n) bf[n] = *(const f16x8*)&mB[c.rB + n * 1024 + c.cb0];
  if (s0) { async_copy16(s0 + c.sdst, c.gBb + k0);
            async_copy16(s0 + 4096 + c.sdst, c.gBb + 64L * c.ldb + k0); }
  BARRIER();
  CLUSTER(af, bf, 0);
  // ---- ph1 ----
#pragma unroll
  for (int i = 0; i < 4; ++i) af[i] = *(const f16x8*)&mA[c.rA + 4096 + i * 1024 + c.cb0];
#pragma unroll
  for (int n = 0; n < 4; ++n) bf2[n] = *(const f16x8*)&mB[c.rB + n * 1024 + c.cb1];
  if (s1) { async_copy16(s1 + c.sdst, c.gAa + kA);
            async_copy16(s1 + 4096 + c.sdst, c.gAa + 64L * c.lda + kA); }
  BARRIER();
  CLUSTER(af, bf, 1);
  // ---- ph2 ----
#pragma unroll
  for (int i = 0; i < 4; ++i) af[i] = *(const f16x8*)&mA[c.rA + i * 1024 + c.cb1];
  if (s2) { async_copy16(s2 + c.sdst, c.gAb + kA);
            async_copy16(s2 + 4096 + c.sdst, c.gAb + 64L * c.lda + kA); }
  BARRIER();
  CLUSTER(af, bf2, 0);
  // ---- ph3 ----
#pragma unroll
  for (int i = 0; i < 4; ++i) af[i] = *(const f16x8*)&mA[c.rA + 4096 + i * 1024 + c.cb1];
  if (s3) { async_copy16(s3 + c.sdst, c.gBa + kB);
            async_copy16(s3 + 4096 + c.sdst, c.gBa + 64L * c.ldb + kB); }
  if (W == 1) { VMCNT(6); } else if (W == 2) { VMCNT(0); }
  BARRIER();
  CLUSTER(af, bf2, 1);
}

// 256x256 tile, BK=64, 8 waves (2M x 4N).  A triple-buffered + B double-
// buffered named LDS (160 KB).  Deep pipeline: stage-to-wait distance 3-6
// phases, vmcnt(6) once per tile.  REQUIRES (K/64 - 2) % 6 == 0 (K=2048).
template<int OUT_F16>
__global__ __launch_bounds__(512, 2)
void gemm256(const f16* __restrict__ A, int lda, long sA,
             const f16* __restrict__ B, int ldb, long sB,
             void* __restrict__ Cv, int ldc, long sC,
             const float* __restrict__ bias, float scale, int K)
{
  __shared__ f16 A0a[8192]; __shared__ f16 A0b[8192];
  __shared__ f16 A1a[8192]; __shared__ f16 A1b[8192];
  __shared__ f16 A2a[8192]; __shared__ f16 A2b[8192];
  __shared__ f16 B0a[8192]; __shared__ f16 B0b[8192];
  __shared__ f16 B1a[8192]; __shared__ f16 B1b[8192];

  const int tid = threadIdx.x, lane = tid & 63, wave = tid >> 6;
  const int wr = wave >> 2, wc = wave & 3;
  const int l15 = lane & 15, lk = lane >> 4;

  // XCD-aware bijective swizzle of the flattened x-y grid
  int lin = blockIdx.y * gridDim.x + blockIdx.x;
  const int nxy = gridDim.x * gridDim.y;
  if ((nxy & 7) == 0) lin = (lin & 7) * (nxy >> 3) + (lin >> 3);
  const int bx = lin % gridDim.x, by = lin / gridDim.x;

  const long brow = (long)by * 256, bcol = (long)bx * 256;
  const int z = blockIdx.z;
  const f16* Ab = A + (long)z * sA;
  const f16* Bb = B + (long)z * sB;

  // staging geometry: row=tid>>3 (+64 second load), global col pre-swizzled
  const int r0  = tid >> 3;
  const int gc8 = (tid & 7) ^ (r0 & 7);
  const int x8  = l15 & 7;

  RCtx c;
  c.sdst = wave * 512;
  c.rA   = l15 * 64;
  c.rB   = ((wc & 1) * 64 + l15) * 64;
  c.cb0  = (lk ^ x8) * 8;
  c.cb1  = ((4 | lk) ^ x8) * 8;
  c.lda  = lda; c.ldb = ldb;
  c.gAa  = Ab + (brow + r0) * (long)lda + gc8 * 8;
  c.gAb  = c.gAa + 128L * lda;
  c.gBa  = Bb + (bcol + r0) * (long)ldb + gc8 * 8;
  c.gBb  = c.gBa + 128L * ldb;

  // per-wave half selections
  const f16* mA0 = wr ? A0b : A0a;
  const f16* mA1 = wr ? A1b : A1a;
  const f16* mA2 = wr ? A2b : A2a;
  const f16* mB0 = (wc & 2) ? B0b : B0a;
  const f16* mB1 = (wc & 2) ? B1b : B1a;

  f32x4 acc[8][4] = {};

#define STGP(BUF, G, LD, KOFF) { \
    async_copy16(BUF + c.sdst,        (G) + (KOFF)); \
    async_copy16(BUF + 4096 + c.sdst, (G) + 64L * (LD) + (KOFF)); }

  // prologue: A0,B0 (landed), A1,B1a (left in flight = 6)
  STGP(A0a, c.gAa, lda, 0);  STGP(A0b, c.gAb, lda, 0);
  STGP(B0a, c.gBa, ldb, 0);  STGP(B0b, c.gBb, ldb, 0);
  STGP(A1a, c.gAa, lda, 64); STGP(A1b, c.gAb, lda, 64);
  STGP(B1a, c.gBa, ldb, 64);
  VMCNT(6);
  BARRIER();

  const int SJ = ((K >> 6) - 2) / 6;     // 5 for K=2048
  for (int J = 0; J < SJ; ++J) {
    const long t0 = 6L * J * 64;         // element k-offset of tile 6J
    tile4<1>(mA0, mB0, B1b, t0 + 64,  A2a, A2b, t0 + 128, B0a, t0 + 128, c, acc);
    tile4<1>(mA1, mB1, B0b, t0 + 128, A0a, A0b, t0 + 192, B1a, t0 + 192, c, acc);
    tile4<1>(mA2, mB0, B1b, t0 + 192, A1a, A1b, t0 + 256, B0a, t0 + 256, c, acc);
    tile4<1>(mA0, mB1, B0b, t0 + 256, A2a, A2b, t0 + 320, B1a, t0 + 320, c, acc);
    tile4<1>(mA1, mB0, B1b, t0 + 320, A0a, A0b, t0 + 384, B0a, t0 + 384, c, acc);
    tile4<1>(mA2, mB1, B0b, t0 + 384, A1a, A1b, t0 + 448, B1a, t0 + 448, c, acc);
  }
  // tail tiles (patterns u=0, u=1 with no forward staging)
  {
    const long kT = (long)(K - 64);      // k of last tile
    tile4<2>(mA0, mB0, B1b, kT, (f16*)0, (f16*)0, 0, (f16*)0, 0, c, acc);
    tile4<0>(mA1, mB1, (f16*)0, 0, (f16*)0, (f16*)0, 0, (f16*)0, 0, c, acc);
  }
#undef STGP

  // epilogue: C/D layout col = lane&15, row = (lane>>4)*4 + j
#pragma unroll
  for (int m = 0; m < 8; ++m) {
#pragma unroll
    for (int n = 0; n < 4; ++n) {
      const long col = bcol + wc * 64 + n * 16 + l15;
      const float bv = bias ? bias[col] : 0.0f;
#pragma unroll
      for (int j = 0; j < 4; ++j) {
        const long row = brow + wr * 128 + m * 16 + lk * 4 + j;
        const float v = acc[m][n][j] * scale + bv;
        if (OUT_F16)
          ((f16*)Cv)[(long)z * sC + row * ldc + col] = (f16)v;
        else
          ((float*)Cv)[(long)z * sC + row * ldc + col] = v;
      }
    }
  }
}

__global__ void cast_f32_f16(const float* __restrict__ in, f16* __restrict__ out, long n) {
  long i = ((long)blockIdx.x * blockDim.x + threadIdx.x) * 4;
  const long stride = (long)gridDim.x * blockDim.x * 4;
  for (; i < n; i += stride) {
    const float4 v = *reinterpret_cast<const float4*>(in + i);
    f16x4 h;
    h.x = (f16)v.x; h.y = (f16)v.y; h.z = (f16)v.z; h.w = (f16)v.w;
    *reinterpret_cast<f16x4*>(out + i) = h;
  }
}

// vt[b][h][s] = qkv[b*2048+s][4096+h]   (extract V and transpose, per batch)
__global__ __launch_bounds__(256)
void transpose_v(const f16* __restrict__ qkv, f16* __restrict__ vt) {
  __shared__ f16 t[32][33];
  const int b = blockIdx.z;
  const int s0 = blockIdx.y * 32, h0 = blockIdx.x * 32;
  const int tx = threadIdx.x, ty = threadIdx.y;  // 32 x 8
  const f16* src = qkv + (long)b * 2048 * 6144 + 4096;
  f16* dst = vt + (long)b * 2048 * 2048;
#pragma unroll
  for (int i = 0; i < 4; ++i)
    t[ty + i * 8][tx] = src[(long)(s0 + ty + i * 8) * 6144 + h0 + tx];
  __syncthreads();
#pragma unroll
  for (int i = 0; i < 4; ++i)
    dst[(long)(h0 + ty + i * 8) * 2048 + s0 + tx] = t[tx][ty + i * 8];
}

// one block per row of 2048 f32 scores; writes f16 probs in-place (row stride 4096 f16)
__global__ __launch_bounds__(256)
void softmax_rows(float* __restrict__ scores) {
  const long row = blockIdx.x;
  float* s = scores + row * 2048;
  const int tid = threadIdx.x;
  const int lane = tid & 63;
  const int wave = tid >> 6;

  const float4 a = *reinterpret_cast<const float4*>(s + tid * 8);
  const float4 b = *reinterpret_cast<const float4*>(s + tid * 8 + 4);
  float v[8] = {a.x, a.y, a.z, a.w, b.x, b.y, b.z, b.w};

  float mx = v[0];
#pragma unroll
  for (int j = 1; j < 8; ++j) mx = fmaxf(mx, v[j]);
#pragma unroll
  for (int off = 32; off >= 1; off >>= 1) mx = fmaxf(mx, __shfl_xor(mx, off));
  __shared__ float red[4];
  if (lane == 0) red[wave] = mx;
  __syncthreads();
  mx = fmaxf(fmaxf(red[0], red[1]), fmaxf(red[2], red[3]));

  float sum = 0.f;
#pragma unroll
  for (int j = 0; j < 8; ++j) { v[j] = __expf(v[j] - mx); sum += v[j]; }
#pragma unroll
  for (int off = 32; off >= 1; off >>= 1) sum += __shfl_xor(sum, off);
  __shared__ float red2[4];
  if (lane == 0) red2[wave] = sum;
  __syncthreads();
  const float inv = 1.0f / (red2[0] + red2[1] + red2[2] + red2[3]);

  f16* p = reinterpret_cast<f16*>(scores) + row * 4096 + tid * 8;
  f16x8 h;
#pragma unroll
  for (int j = 0; j < 8; ++j) h[j] = (f16)(v[j] * inv);
  *reinterpret_cast<f16x8*>(p) = h;
}

extern "C" void kernel_launch(void* const* d_in, const int* in_sizes, int n_in,
                              void* d_out, int out_size, void* d_ws, size_t ws_size,
                              hipStream_t stream) {
  const float* x     = (const float*)d_in[0];  // [4,2048,2048]
  const float* w_qkv = (const float*)d_in[1];  // [6144,2048]
  const float* b_qkv = (const float*)d_in[2];  // [6144]
  const float* w_out = (const float*)d_in[3];  // [2048,2048]
  const float* b_out = (const float*)d_in[4];  // [2048]
  float* out = (float*)d_out;                  // [4,2048,2048] f32

  char* ws = (char*)d_ws;
  f16*   Xh    = (f16*)(ws + 0);           //  33.5 MB  [8192][2048]
  f16*   Wqkvh = (f16*)(ws + 33554432L);   //  25.2 MB  [6144][2048]
  f16*   Wouth = (f16*)(ws + 58720256L);   //   8.4 MB  [2048][2048]
  f16*   QKV   = (f16*)(ws + 67108864L);   // 100.7 MB  [8192][6144]
  float* SC    = (float*)(ws + 167772160L);//  67.1 MB  [4][2048][2048] f32 (probs f16 in-place)
  f16*   VT    = (f16*)(ws + 234881024L);  //  33.5 MB  [4][2048][2048]
  f16*   CTX   = Xh;                       // reuse X region after gemm1

  const float inv_sqrt_h = 0.022097086912079608f;  // 1/sqrt(2048)

  cast_f32_f16<<<2048, 256, 0, stream>>>(x,     Xh,    16777216L);
  cast_f32_f16<<<2048, 256, 0, stream>>>(w_qkv, Wqkvh, 12582912L);
  cast_f32_f16<<<1024, 256, 0, stream>>>(w_out, Wouth, 4194304L);

  // qkv = x @ w_qkv^T + b_qkv   [8192 x 6144]
  gemm256<1><<<dim3(24, 32, 1), 512, 0, stream>>>(
      Xh, 2048, 0, Wqkvh, 2048, 0, QKV, 6144, 0, b_qkv, 1.0f, 2048);

  // scores = Q @ K^T / sqrt(H)  per batch  [2048 x 2048] f32
  gemm256<0><<<dim3(8, 8, 4), 512, 0, stream>>>(
      QKV, 6144, 2048L * 6144, QKV + 2048, 6144, 2048L * 6144,
      SC, 2048, 2048L * 2048, nullptr, inv_sqrt_h, 2048);

  transpose_v<<<dim3(64, 64, 4), dim3(32, 8), 0, stream>>>(QKV, VT);

  softmax_rows<<<8192, 256, 0, stream>>>(SC);

  // context = P @ V  per batch (probs f16 in-place in SC, row stride 4096)
  gemm256<1><<<dim3(8, 8, 4), 512, 0, stream>>>(
      (const f16*)SC, 4096, 2048L * 4096, VT, 2048, 2048L * 2048,
      CTX, 2048, 2048L * 2048, nullptr, 1.0f, 2048);

  // out = context @ w_out^T + b_out   [8192 x 2048] f32
  gemm256<0><<<dim3(8, 32, 1), 512, 0, stream>>>(
      CTX, 2048, 0, Wouth, 2048, 0, out, 2048, 0, b_out, 1.0f, 2048);
}

// Round 11
// 477.228 us; speedup vs baseline: 1.5543x; 1.5543x over previous
//
#include <hip/hip_runtime.h>
#include <cstdint>

typedef _Float16 f16;
typedef __attribute__((ext_vector_type(8))) _Float16 f16x8;
typedef __attribute__((ext_vector_type(4))) _Float16 f16x4;
typedef __attribute__((ext_vector_type(4))) float f32x4;

typedef __attribute__((address_space(1))) void gvoid_t;
typedef __attribute__((address_space(3))) void lvoid_t;

// async global->LDS, 16B per lane. LDS dest wave-uniform base; HW adds lane*16.
__device__ __forceinline__ void async_copy16(void* lds, const void* g) {
  __builtin_amdgcn_global_load_lds((gvoid_t*)(uintptr_t)g, (lvoid_t*)lds, 16, 0, 0);
}

#define BARRIER()   __builtin_amdgcn_s_barrier()
#define SCHEDBAR()  __builtin_amdgcn_sched_barrier(0)
#define VMCNT(n)    do { SCHEDBAR(); asm volatile("s_waitcnt vmcnt(" #n ")"); SCHEDBAR(); } while (0)

#define MFMA16(a, b, c) __builtin_amdgcn_mfma_f32_16x16x32_f16((a), (b), (c), 0, 0, 0)

// cursor-based staging state: one pointer pair per staging stream; advanced
// +64 elems per tile in place (16 long-lived VGPRs, no per-call temps --
// round-10 spill fix).
struct RCtx {
  int sdst, rA, rB, cb0, cb1;
  const f16 *cBb0, *cBb1, *cAa0, *cAa1, *cAb0, *cAb1, *cBa0, *cBa1;
};

#define CLUSTER(AF, BF, Q) { \
    __builtin_amdgcn_s_setprio(1); \
    _Pragma("unroll") \
    for (int n = 0; n < 4; ++n) { \
      _Pragma("unroll") \
      for (int i = 0; i < 4; ++i) \
        acc[(Q)*4 + i][n] = MFMA16(AF[i], BF[n], acc[(Q)*4 + i][n]); \
    } \
    __builtin_amdgcn_s_setprio(0); }

// One K-tile (K=64), 4 phases {reads; stage; [vmcnt]; barrier; 16 MFMA}.
// Reads balanced 8/8/4/4 via kk-split.  Stages per phase (cursor streams):
// ph0 Bb -> B(t+1)b, ph1 Aa -> A(t+2)a, ph2 Ab -> A(t+2)b, ph3 Ba -> B(t+2)a.
// W=1 -> vmcnt(6) at ph3 (drains A(t+1)+B(t+1); keeps A(t+2)a,b + B(t+2)a in
// flight); W=2 -> vmcnt(0); W=0 -> none.
template<int W>
__device__ __forceinline__ void tile4(const f16* mA, const f16* mB,
    f16* s0, f16* s1, f16* s2, f16* s3, RCtx& c, f32x4 (&acc)[8][4])
{
  f16x8 af[4], bf[4], bf2[4];
  // ---- ph0 ----
#pragma unroll
  for (int i = 0; i < 4; ++i) af[i] = *(const f16x8*)&mA[c.rA + i * 1024 + c.cb0];
#pragma unroll
  for (int n = 0; n < 4; ++n) bf[n] = *(const f16x8*)&mB[c.rB + n * 1024 + c.cb0];
  if (s0) { async_copy16(s0 + c.sdst, c.cBb0); async_copy16(s0 + 4096 + c.sdst, c.cBb1);
            c.cBb0 += 64; c.cBb1 += 64; }
  BARRIER();
  CLUSTER(af, bf, 0);
  // ---- ph1 ----
#pragma unroll
  for (int i = 0; i < 4; ++i) af[i] = *(const f16x8*)&mA[c.rA + 4096 + i * 1024 + c.cb0];
#pragma unroll
  for (int n = 0; n < 4; ++n) bf2[n] = *(const f16x8*)&mB[c.rB + n * 1024 + c.cb1];
  if (s1) { async_copy16(s1 + c.sdst, c.cAa0); async_copy16(s1 + 4096 + c.sdst, c.cAa1);
            c.cAa0 += 64; c.cAa1 += 64; }
  BARRIER();
  CLUSTER(af, bf, 1);
  // ---- ph2 ----
#pragma unroll
  for (int i = 0; i < 4; ++i) af[i] = *(const f16x8*)&mA[c.rA + i * 1024 + c.cb1];
  if (s2) { async_copy16(s2 + c.sdst, c.cAb0); async_copy16(s2 + 4096 + c.sdst, c.cAb1);
            c.cAb0 += 64; c.cAb1 += 64; }
  BARRIER();
  CLUSTER(af, bf2, 0);
  // ---- ph3 ----
#pragma unroll
  for (int i = 0; i < 4; ++i) af[i] = *(const f16x8*)&mA[c.rA + 4096 + i * 1024 + c.cb1];
  if (s3) { async_copy16(s3 + c.sdst, c.cBa0); async_copy16(s3 + 4096 + c.sdst, c.cBa1);
            c.cBa0 += 64; c.cBa1 += 64; }
  if (W == 1) { VMCNT(6); } else if (W == 2) { VMCNT(0); }
  BARRIER();
  CLUSTER(af, bf2, 1);
}

// 256x256 tile, BK=64, 8 waves (2M x 4N).  A triple- + B double-buffered named
// LDS (160 KB).  Stage-to-wait distance 3-6 phases, vmcnt(6) once per tile.
// REQUIRES (K/64 - 2) % 6 == 0 (K=2048).
template<int OUT_F16>
__global__ __launch_bounds__(512, 2)
void gemm256(const f16* __restrict__ A, int lda, long sA,
             const f16* __restrict__ B, int ldb, long sB,
             void* __restrict__ Cv, int ldc, long sC,
             const float* __restrict__ bias, float scale, int K)
{
  __shared__ f16 A0a[8192]; __shared__ f16 A0b[8192];
  __shared__ f16 A1a[8192]; __shared__ f16 A1b[8192];
  __shared__ f16 A2a[8192]; __shared__ f16 A2b[8192];
  __shared__ f16 B0a[8192]; __shared__ f16 B0b[8192];
  __shared__ f16 B1a[8192]; __shared__ f16 B1b[8192];

  const int tid = threadIdx.x, lane = tid & 63, wave = tid >> 6;
  const int wr = wave >> 2, wc = wave & 3;
  const int l15 = lane & 15, lk = lane >> 4;

  // XCD-aware bijective swizzle of the flattened x-y grid
  int lin = blockIdx.y * gridDim.x + blockIdx.x;
  const int nxy = gridDim.x * gridDim.y;
  if ((nxy & 7) == 0) lin = (lin & 7) * (nxy >> 3) + (lin >> 3);
  const int bx = lin % gridDim.x, by = lin / gridDim.x;

  const long brow = (long)by * 256, bcol = (long)bx * 256;
  const int z = blockIdx.z;
  const f16* Ab = A + (long)z * sA;
  const f16* Bb = B + (long)z * sB;

  // staging geometry: row=tid>>3 (+64 second load), global col pre-swizzled
  const int r0  = tid >> 3;
  const int gc8 = (tid & 7) ^ (r0 & 7);
  const int x8  = l15 & 7;

  const f16* gAa = Ab + (brow + r0) * (long)lda + gc8 * 8;
  const f16* gAb = gAa + 128L * lda;
  const f16* gBa = Bb + (bcol + r0) * (long)ldb + gc8 * 8;
  const f16* gBb = gBa + 128L * ldb;

  RCtx c;
  c.sdst = wave * 512;
  c.rA   = l15 * 64;
  c.rB   = ((wc & 1) * 64 + l15) * 64;
  c.cb0  = (lk ^ x8) * 8;
  c.cb1  = ((4 | lk) ^ x8) * 8;
  // cursors: next staging source per stream (element k shown)
  c.cBb0 = gBb + 64;              c.cBb1 = gBb + 64L * ldb + 64;    // B(t+1)b @64
  c.cAa0 = gAa + 128;             c.cAa1 = gAa + 64L * lda + 128;   // A(t+2)a @128
  c.cAb0 = gAb + 128;             c.cAb1 = gAb + 64L * lda + 128;   // A(t+2)b @128
  c.cBa0 = gBa + 128;             c.cBa1 = gBa + 64L * ldb + 128;   // B(t+2)a @128

  // per-wave half selections
  const f16* mA0 = wr ? A0b : A0a;
  const f16* mA1 = wr ? A1b : A1a;
  const f16* mA2 = wr ? A2b : A2a;
  const f16* mB0 = (wc & 2) ? B0b : B0a;
  const f16* mB1 = (wc & 2) ? B1b : B1a;

  f32x4 acc[8][4] = {};

#define STGP(BUF, G, LD, KOFF) { \
    async_copy16(BUF + c.sdst,        (G) + (KOFF)); \
    async_copy16(BUF + 4096 + c.sdst, (G) + 64L * (LD) + (KOFF)); }

  // prologue: A0,B0 (landed), A1,B1a (left in flight = 6)
  STGP(A0a, gAa, lda, 0);  STGP(A0b, gAb, lda, 0);
  STGP(B0a, gBa, ldb, 0);  STGP(B0b, gBb, ldb, 0);
  STGP(A1a, gAa, lda, 64); STGP(A1b, gAb, lda, 64);
  STGP(B1a, gBa, ldb, 64);
  VMCNT(6);
  BARRIER();
#undef STGP

  const int SJ = ((K >> 6) - 2) / 6;     // 5 for K=2048
  for (int J = 0; J < SJ; ++J) {
    tile4<1>(mA0, mB0, B1b, A2a, A2b, B0a, c, acc);
    tile4<1>(mA1, mB1, B0b, A0a, A0b, B1a, c, acc);
    tile4<1>(mA2, mB0, B1b, A1a, A1b, B0a, c, acc);
    tile4<1>(mA0, mB1, B0b, A2a, A2b, B1a, c, acc);
    tile4<1>(mA1, mB0, B1b, A0a, A0b, B0a, c, acc);
    tile4<1>(mA2, mB1, B0b, A1a, A1b, B1a, c, acc);
  }
  // tail tiles t = NT-2, NT-1
  tile4<2>(mA0, mB0, B1b, (f16*)0, (f16*)0, (f16*)0, c, acc);
  tile4<0>(mA1, mB1, (f16*)0, (f16*)0, (f16*)0, (f16*)0, c, acc);

  // epilogue: C/D layout col = lane&15, row = (lane>>4)*4 + j
#pragma unroll
  for (int m = 0; m < 8; ++m) {
#pragma unroll
    for (int n = 0; n < 4; ++n) {
      const long col = bcol + wc * 64 + n * 16 + l15;
      const float bv = bias ? bias[col] : 0.0f;
#pragma unroll
      for (int j = 0; j < 4; ++j) {
        const long row = brow + wr * 128 + m * 16 + lk * 4 + j;
        const float v = acc[m][n][j] * scale + bv;
        if (OUT_F16)
          ((f16*)Cv)[(long)z * sC + row * ldc + col] = (f16)v;
        else
          ((float*)Cv)[(long)z * sC + row * ldc + col] = v;
      }
    }
  }
}

__global__ void cast_f32_f16(const float* __restrict__ in, f16* __restrict__ out, long n) {
  long i = ((long)blockIdx.x * blockDim.x + threadIdx.x) * 4;
  const long stride = (long)gridDim.x * blockDim.x * 4;
  for (; i < n; i += stride) {
    const float4 v = *reinterpret_cast<const float4*>(in + i);
    f16x4 h;
    h.x = (f16)v.x; h.y = (f16)v.y; h.z = (f16)v.z; h.w = (f16)v.w;
    *reinterpret_cast<f16x4*>(out + i) = h;
  }
}

// vt[b][h][s] = qkv[b*2048+s][4096+h]   (extract V and transpose, per batch)
__global__ __launch_bounds__(256)
void transpose_v(const f16* __restrict__ qkv, f16* __restrict__ vt) {
  __shared__ f16 t[32][33];
  const int b = blockIdx.z;
  const int s0 = blockIdx.y * 32, h0 = blockIdx.x * 32;
  const int tx = threadIdx.x, ty = threadIdx.y;  // 32 x 8
  const f16* src = qkv + (long)b * 2048 * 6144 + 4096;
  f16* dst = vt + (long)b * 2048 * 2048;
#pragma unroll
  for (int i = 0; i < 4; ++i)
    t[ty + i * 8][tx] = src[(long)(s0 + ty + i * 8) * 6144 + h0 + tx];
  __syncthreads();
#pragma unroll
  for (int i = 0; i < 4; ++i)
    dst[(long)(h0 + ty + i * 8) * 2048 + s0 + tx] = t[tx][ty + i * 8];
}

// one block per row of 2048 f32 scores; writes f16 probs in-place (row stride 4096 f16)
__global__ __launch_bounds__(256)
void softmax_rows(float* __restrict__ scores) {
  const long row = blockIdx.x;
  float* s = scores + row * 2048;
  const int tid = threadIdx.x;
  const int lane = tid & 63;
  const int wave = tid >> 6;

  const float4 a = *reinterpret_cast<const float4*>(s + tid * 8);
  const float4 b = *reinterpret_cast<const float4*>(s + tid * 8 + 4);
  float v[8] = {a.x, a.y, a.z, a.w, b.x, b.y, b.z, b.w};

  float mx = v[0];
#pragma unroll
  for (int j = 1; j < 8; ++j) mx = fmaxf(mx, v[j]);
#pragma unroll
  for (int off = 32; off >= 1; off >>= 1) mx = fmaxf(mx, __shfl_xor(mx, off));
  __shared__ float red[4];
  if (lane == 0) red[wave] = mx;
  __syncthreads();
  mx = fmaxf(fmaxf(red[0], red[1]), fmaxf(red[2], red[3]));

  float sum = 0.f;
#pragma unroll
  for (int j = 0; j < 8; ++j) { v[j] = __expf(v[j] - mx); sum += v[j]; }
#pragma unroll
  for (int off = 32; off >= 1; off >>= 1) sum += __shfl_xor(sum, off);
  __shared__ float red2[4];
  if (lane == 0) red2[wave] = sum;
  __syncthreads();
  const float inv = 1.0f / (red2[0] + red2[1] + red2[2] + red2[3]);

  f16* p = reinterpret_cast<f16*>(scores) + row * 4096 + tid * 8;
  f16x8 h;
#pragma unroll
  for (int j = 0; j < 8; ++j) h[j] = (f16)(v[j] * inv);
  *reinterpret_cast<f16x8*>(p) = h;
}

extern "C" void kernel_launch(void* const* d_in, const int* in_sizes, int n_in,
                              void* d_out, int out_size, void* d_ws, size_t ws_size,
                              hipStream_t stream) {
  const float* x     = (const float*)d_in[0];  // [4,2048,2048]
  const float* w_qkv = (const float*)d_in[1];  // [6144,2048]
  const float* b_qkv = (const float*)d_in[2];  // [6144]
  const float* w_out = (const float*)d_in[3];  // [2048,2048]
  const float* b_out = (const float*)d_in[4];  // [2048]
  float* out = (float*)d_out;                  // [4,2048,2048] f32

  char* ws = (char*)d_ws;
  f16*   Xh    = (f16*)(ws + 0);           //  33.5 MB  [8192][2048]
  f16*   Wqkvh = (f16*)(ws + 33554432L);   //  25.2 MB  [6144][2048]
  f16*   Wouth = (f16*)(ws + 58720256L);   //   8.4 MB  [2048][2048]
  f16*   QKV   = (f16*)(ws + 67108864L);   // 100.7 MB  [8192][6144]
  float* SC    = (float*)(ws + 167772160L);//  67.1 MB  [4][2048][2048] f32 (probs f16 in-place)
  f16*   VT    = (f16*)(ws + 234881024L);  //  33.5 MB  [4][2048][2048]
  f16*   CTX   = Xh;                       // reuse X region after gemm1

  const float inv_sqrt_h = 0.022097086912079608f;  // 1/sqrt(2048)

  cast_f32_f16<<<2048, 256, 0, stream>>>(x,     Xh,    16777216L);
  cast_f32_f16<<<2048, 256, 0, stream>>>(w_qkv, Wqkvh, 12582912L);
  cast_f32_f16<<<1024, 256, 0, stream>>>(w_out, Wouth, 4194304L);

  // qkv = x @ w_qkv^T + b_qkv   [8192 x 6144]
  gemm256<1><<<dim3(24, 32, 1), 512, 0, stream>>>(
      Xh, 2048, 0, Wqkvh, 2048, 0, QKV, 6144, 0, b_qkv, 1.0f, 2048);

  // scores = Q @ K^T / sqrt(H)  per batch  [2048 x 2048] f32
  gemm256<0><<<dim3(8, 8, 4), 512, 0, stream>>>(
      QKV, 6144, 2048L * 6144, QKV + 2048, 6144, 2048L * 6144,
      SC, 2048, 2048L * 2048, nullptr, inv_sqrt_h, 2048);

  transpose_v<<<dim3(64, 64, 4), dim3(32, 8), 0, stream>>>(QKV, VT);

  softmax_rows<<<8192, 256, 0, stream>>>(SC);

  // context = P @ V  per batch (probs f16 in-place in SC, row stride 4096)
  gemm256<1><<<dim3(8, 8, 4), 512, 0, stream>>>(
      (const f16*)SC, 4096, 2048L * 4096, VT, 2048, 2048L * 2048,
      CTX, 2048, 2048L * 2048, nullptr, 1.0f, 2048);

  // out = context @ w_out^T + b_out   [8192 x 2048] f32
  gemm256<0><<<dim3(8, 32, 1), 512, 0, stream>>>(
      CTX, 2048, 0, Wouth, 2048, 0, out, 2048, 0, b_out, 1.0f, 2048);
}

// Round 12
// 466.224 us; speedup vs baseline: 1.5910x; 1.0236x over previous
//
#include <hip/hip_runtime.h>
#include <cstdint>

typedef _Float16 f16;
typedef __attribute__((ext_vector_type(8))) _Float16 f16x8;
typedef __attribute__((ext_vector_type(4))) _Float16 f16x4;
typedef __attribute__((ext_vector_type(4))) float f32x4;

typedef __attribute__((address_space(1))) void gvoid_t;
typedef __attribute__((address_space(3))) void lvoid_t;

// async global->LDS, 16B per lane. LDS dest wave-uniform base; HW adds lane*16.
__device__ __forceinline__ void async_copy16(void* lds, const void* g) {
  __builtin_amdgcn_global_load_lds((gvoid_t*)(uintptr_t)g, (lvoid_t*)lds, 16, 0, 0);
}

#define BARRIER()   __builtin_amdgcn_s_barrier()
#define SCHEDBAR()  __builtin_amdgcn_sched_barrier(0)
#define VMCNT(n)    do { SCHEDBAR(); asm volatile("s_waitcnt vmcnt(" #n ")"); SCHEDBAR(); } while (0)

#define MFMA16(a, b, c) __builtin_amdgcn_mfma_f32_16x16x32_f16((a), (b), (c), 0, 0, 0)

// 256x256 tile, BK=64, 8 waves (2M x 4N), 8-phase schedule (r8 skeleton), ONE
// barrier per phase, reads balanced 8/4/8/4 via kk-split phases (m-half x kk):
//   ph0 {bf(kk0)+af(m0-3,kk0)} ph1 {af(m4-7,kk0)} ph2 {bf2(kk1)+af(m0-3,kk1)}
//   ph3 {af(m4-7,kk1)} -- max per-phase LDS ~768cy ~ MFMA 620cy (was 1152).
// Stage slots + waits identical to r8: ph0 BH1b ph1 AH1a ph2 AH1b ph3 BH0a+W1
// ph4 BH0b ph5 AH0a ph6 AH0b ph7 BH1a+W2; W = vmcnt(2).
template<int OUT_F16>
__global__ __launch_bounds__(512, 2)
void gemm256(const f16* __restrict__ A, int lda, long sA,
             const f16* __restrict__ B, int ldb, long sB,
             void* __restrict__ Cv, int ldc, long sC,
             const float* __restrict__ bias, float scale, int K)
{
  __shared__ f16 AH0a[8192]; __shared__ f16 AH0b[8192];
  __shared__ f16 AH1a[8192]; __shared__ f16 AH1b[8192];
  __shared__ f16 BH0a[8192]; __shared__ f16 BH0b[8192];
  __shared__ f16 BH1a[8192]; __shared__ f16 BH1b[8192];

  const int tid = threadIdx.x, lane = tid & 63, wave = tid >> 6;
  const int wr = wave >> 2, wc = wave & 3;       // wave -> (M half, N quarter)
  const int l15 = lane & 15, lk = lane >> 4;

  // XCD-aware bijective swizzle of the flattened x-y grid (z untouched)
  int lin = blockIdx.y * gridDim.x + blockIdx.x;
  const int nxy = gridDim.x * gridDim.y;
  if ((nxy & 7) == 0) lin = (lin & 7) * (nxy >> 3) + (lin >> 3);
  const int bx = lin % gridDim.x, by = lin / gridDim.x;

  const long brow = (long)by * 256, bcol = (long)bx * 256;
  const int z = blockIdx.z;
  const f16* Ab = A + (long)z * sA;
  const f16* Bb = B + (long)z * sB;

  // staging: slot=tid covers (row=tid>>3 [+64 for 2nd instr], col8=tid&7) of a
  // 128x64 half; global col-block pre-swizzled gc8 = (tid&7)^(row&7) so the
  // ds_read side applies the same XOR (both-sides-or-neither).
  const int r0  = tid >> 3;                  // 0..63
  const int gc8 = (tid & 7) ^ (r0 & 7);      // (r0+64)&7 == r0&7
  const int sdst = wave * 512;               // wave-uniform elem offset

  const f16* gAa = Ab + (brow + r0) * (long)lda + gc8 * 8;
  const f16* gAb = gAa + 128L * lda;
  const f16* gBa = Bb + (bcol + r0) * (long)ldb + gc8 * 8;
  const f16* gBb = gBa + 128L * ldb;

#define STG(BUF, G, LD, KOFF) { \
    async_copy16(BUF + sdst,        (G) + (KOFF)); \
    async_copy16(BUF + 4096 + sdst, (G) + 64L * (LD) + (KOFF)); }

  // per-wave source halves
  const f16* myA0 = wr ? AH0b : AH0a;
  const f16* myA1 = wr ? AH1b : AH1a;
  const f16* myB0 = (wc & 2) ? BH0b : BH0a;
  const f16* myB1 = (wc & 2) ? BH1b : BH1a;

  // frag read addressing: lr = m16 + l15 (m16 mult of 16 => lr&7 == l15&7)
  const int x8   = l15 & 7;
  const int cb0  = (lk ^ x8) * 8;            // kk=0 col bytes/2
  const int cb1  = ((4 | lk) ^ x8) * 8;      // kk=1
  const int lbA  = l15 * 64;
  const int lbB  = ((wc & 1) * 64 + l15) * 64;

// read 4 A-frags for m-half MH (0=m0-3, 1=m4-7) at kk col offset CB
#define RDA(AF, SRC, MH, CB) { \
    AF[0] = *(const f16x8*)&(SRC)[lbA + ((MH)*4 + 0) * 1024 + (CB)]; \
    AF[1] = *(const f16x8*)&(SRC)[lbA + ((MH)*4 + 1) * 1024 + (CB)]; \
    AF[2] = *(const f16x8*)&(SRC)[lbA + ((MH)*4 + 2) * 1024 + (CB)]; \
    AF[3] = *(const f16x8*)&(SRC)[lbA + ((MH)*4 + 3) * 1024 + (CB)]; }

// read 4 B-frags at kk col offset CB
#define RDB(BF, SRC, CB) { \
    BF[0] = *(const f16x8*)&(SRC)[lbB + 0 * 1024 + (CB)]; \
    BF[1] = *(const f16x8*)&(SRC)[lbB + 1 * 1024 + (CB)]; \
    BF[2] = *(const f16x8*)&(SRC)[lbB + 2 * 1024 + (CB)]; \
    BF[3] = *(const f16x8*)&(SRC)[lbB + 3 * 1024 + (CB)]; }

// 16 MFMA: m-half MH x 4n, one kk
#define CL(AF, BF, MH) { \
    __builtin_amdgcn_s_setprio(1); \
    _Pragma("unroll") \
    for (int n = 0; n < 4; ++n) { \
      _Pragma("unroll") \
      for (int i = 0; i < 4; ++i) \
        acc[(MH)*4 + i][n] = MFMA16(AF[i], BF[n], acc[(MH)*4 + i][n]); \
    } \
    __builtin_amdgcn_s_setprio(0); }

  f32x4 acc[8][4] = {};
  f16x8 af[4], bf[4], bf2[4];
  const int NIT = K >> 7;                    // K/128

  // prologue: B0, A0, B1-half-a (10 instrs); vmcnt(2) leaves BH1a in flight.
  STG(BH0a, gBa, ldb, 0);  STG(BH0b, gBb, ldb, 0);
  STG(AH0a, gAa, lda, 0);  STG(AH0b, gAb, lda, 0);
  STG(BH1a, gBa, ldb, 64);
  VMCNT(2);
  BARRIER();

  for (int J = 0; J < NIT; ++J) {
    const long k1 = 128L * J + 64;           // tile 2J+1
    const long k2 = 128L * J + 128;          // tile 2J+2
    const long k3 = 128L * J + 192;          // tile 2J+3
    const bool st = (J + 1 < NIT);

    // ---- K-tile T=2J (buf0): phases 0-3 ----
    RDB(bf, myB0, cb0); RDA(af, myA0, 0, cb0);
    STG(BH1b, gBb, ldb, k1);
    BARRIER(); CL(af, bf, 0);

    RDA(af, myA0, 1, cb0);
    STG(AH1a, gAa, lda, k1);
    BARRIER(); CL(af, bf, 1);

    RDB(bf2, myB0, cb1); RDA(af, myA0, 0, cb1);
    STG(AH1b, gAb, lda, k1);
    BARRIER(); CL(af, bf2, 0);

    RDA(af, myA0, 1, cb1);
    if (st) { STG(BH0a, gBa, ldb, k2); VMCNT(2); } else { VMCNT(0); }  // W1
    BARRIER(); CL(af, bf2, 1);

    // ---- K-tile T+1 (buf1): phases 4-7 ----
    RDB(bf, myB1, cb0); RDA(af, myA1, 0, cb0);
    if (st) STG(BH0b, gBb, ldb, k2);
    BARRIER(); CL(af, bf, 0);

    RDA(af, myA1, 1, cb0);
    if (st) STG(AH0a, gAa, lda, k2);
    BARRIER(); CL(af, bf, 1);

    RDB(bf2, myB1, cb1); RDA(af, myA1, 0, cb1);
    if (st) STG(AH0b, gAb, lda, k2);
    BARRIER(); CL(af, bf2, 0);

    RDA(af, myA1, 1, cb1);
    if (st) { STG(BH1a, gBa, ldb, k3); VMCNT(2); }                     // W2
    BARRIER(); CL(af, bf2, 1);
  }

  // epilogue: C/D layout col = lane&15, row = (lane>>4)*4 + j
#pragma unroll
  for (int m = 0; m < 8; ++m) {
#pragma unroll
    for (int n = 0; n < 4; ++n) {
      const long col = bcol + wc * 64 + n * 16 + l15;
      const float bv = bias ? bias[col] : 0.0f;
#pragma unroll
      for (int j = 0; j < 4; ++j) {
        const long row = brow + wr * 128 + m * 16 + lk * 4 + j;
        const float v = acc[m][n][j] * scale + bv;
        if (OUT_F16)
          ((f16*)Cv)[(long)z * sC + row * ldc + col] = (f16)v;
        else
          ((float*)Cv)[(long)z * sC + row * ldc + col] = v;
      }
    }
  }
#undef STG
#undef RDA
#undef RDB
#undef CL
}

__global__ void cast_f32_f16(const float* __restrict__ in, f16* __restrict__ out, long n) {
  long i = ((long)blockIdx.x * blockDim.x + threadIdx.x) * 4;
  const long stride = (long)gridDim.x * blockDim.x * 4;
  for (; i < n; i += stride) {
    const float4 v = *reinterpret_cast<const float4*>(in + i);
    f16x4 h;
    h.x = (f16)v.x; h.y = (f16)v.y; h.z = (f16)v.z; h.w = (f16)v.w;
    *reinterpret_cast<f16x4*>(out + i) = h;
  }
}

// vt[b][h][s] = qkv[b*2048+s][4096+h]   (extract V and transpose, per batch)
__global__ __launch_bounds__(256)
void transpose_v(const f16* __restrict__ qkv, f16* __restrict__ vt) {
  __shared__ f16 t[32][33];
  const int b = blockIdx.z;
  const int s0 = blockIdx.y * 32, h0 = blockIdx.x * 32;
  const int tx = threadIdx.x, ty = threadIdx.y;  // 32 x 8
  const f16* src = qkv + (long)b * 2048 * 6144 + 4096;
  f16* dst = vt + (long)b * 2048 * 2048;
#pragma unroll
  for (int i = 0; i < 4; ++i)
    t[ty + i * 8][tx] = src[(long)(s0 + ty + i * 8) * 6144 + h0 + tx];
  __syncthreads();
#pragma unroll
  for (int i = 0; i < 4; ++i)
    dst[(long)(h0 + ty + i * 8) * 2048 + s0 + tx] = t[tx][ty + i * 8];
}

// one block per row of 2048 f32 scores; writes f16 probs in-place (row stride 4096 f16)
__global__ __launch_bounds__(256)
void softmax_rows(float* __restrict__ scores) {
  const long row = blockIdx.x;
  float* s = scores + row * 2048;
  const int tid = threadIdx.x;
  const int lane = tid & 63;
  const int wave = tid >> 6;

  const float4 a = *reinterpret_cast<const float4*>(s + tid * 8);
  const float4 b = *reinterpret_cast<const float4*>(s + tid * 8 + 4);
  float v[8] = {a.x, a.y, a.z, a.w, b.x, b.y, b.z, b.w};

  float mx = v[0];
#pragma unroll
  for (int j = 1; j < 8; ++j) mx = fmaxf(mx, v[j]);
#pragma unroll
  for (int off = 32; off >= 1; off >>= 1) mx = fmaxf(mx, __shfl_xor(mx, off));
  __shared__ float red[4];
  if (lane == 0) red[wave] = mx;
  __syncthreads();
  mx = fmaxf(fmaxf(red[0], red[1]), fmaxf(red[2], red[3]));

  float sum = 0.f;
#pragma unroll
  for (int j = 0; j < 8; ++j) { v[j] = __expf(v[j] - mx); sum += v[j]; }
#pragma unroll
  for (int off = 32; off >= 1; off >>= 1) sum += __shfl_xor(sum, off);
  __shared__ float red2[4];
  if (lane == 0) red2[wave] = sum;
  __syncthreads();
  const float inv = 1.0f / (red2[0] + red2[1] + red2[2] + red2[3]);

  f16* p = reinterpret_cast<f16*>(scores) + row * 4096 + tid * 8;
  f16x8 h;
#pragma unroll
  for (int j = 0; j < 8; ++j) h[j] = (f16)(v[j] * inv);
  *reinterpret_cast<f16x8*>(p) = h;
}

extern "C" void kernel_launch(void* const* d_in, const int* in_sizes, int n_in,
                              void* d_out, int out_size, void* d_ws, size_t ws_size,
                              hipStream_t stream) {
  const float* x     = (const float*)d_in[0];  // [4,2048,2048]
  const float* w_qkv = (const float*)d_in[1];  // [6144,2048]
  const float* b_qkv = (const float*)d_in[2];  // [6144]
  const float* w_out = (const float*)d_in[3];  // [2048,2048]
  const float* b_out = (const float*)d_in[4];  // [2048]
  float* out = (float*)d_out;                  // [4,2048,2048] f32

  char* ws = (char*)d_ws;
  f16*   Xh    = (f16*)(ws + 0);           //  33.5 MB  [8192][2048]
  f16*   Wqkvh = (f16*)(ws + 33554432L);   //  25.2 MB  [6144][2048]
  f16*   Wouth = (f16*)(ws + 58720256L);   //   8.4 MB  [2048][2048]
  f16*   QKV   = (f16*)(ws + 67108864L);   // 100.7 MB  [8192][6144]
  float* SC    = (float*)(ws + 167772160L);//  67.1 MB  [4][2048][2048] f32 (probs f16 in-place)
  f16*   VT    = (f16*)(ws + 234881024L);  //  33.5 MB  [4][2048][2048]
  f16*   CTX   = Xh;                       // reuse X region after gemm1

  const float inv_sqrt_h = 0.022097086912079608f;  // 1/sqrt(2048)

  cast_f32_f16<<<2048, 256, 0, stream>>>(x,     Xh,    16777216L);
  cast_f32_f16<<<2048, 256, 0, stream>>>(w_qkv, Wqkvh, 12582912L);
  cast_f32_f16<<<1024, 256, 0, stream>>>(w_out, Wouth, 4194304L);

  // qkv = x @ w_qkv^T + b_qkv   [8192 x 6144]
  gemm256<1><<<dim3(24, 32, 1), 512, 0, stream>>>(
      Xh, 2048, 0, Wqkvh, 2048, 0, QKV, 6144, 0, b_qkv, 1.0f, 2048);

  // scores = Q @ K^T / sqrt(H)  per batch  [2048 x 2048] f32
  gemm256<0><<<dim3(8, 8, 4), 512, 0, stream>>>(
      QKV, 6144, 2048L * 6144, QKV + 2048, 6144, 2048L * 6144,
      SC, 2048, 2048L * 2048, nullptr, inv_sqrt_h, 2048);

  transpose_v<<<dim3(64, 64, 4), dim3(32, 8), 0, stream>>>(QKV, VT);

  softmax_rows<<<8192, 256, 0, stream>>>(SC);

  // context = P @ V  per batch (probs f16 in-place in SC, row stride 4096)
  gemm256<1><<<dim3(8, 8, 4), 512, 0, stream>>>(
      (const f16*)SC, 4096, 2048L * 4096, VT, 2048, 2048L * 2048,
      CTX, 2048, 2048L * 2048, nullptr, 1.0f, 2048);

  // out = context @ w_out^T + b_out   [8192 x 2048] f32
  gemm256<0><<<dim3(8, 32, 1), 512, 0, stream>>>(
      CTX, 2048, 0, Wouth, 2048, 0, out, 2048, 0, b_out, 1.0f, 2048);
}

// Round 13
// 450.475 us; speedup vs baseline: 1.6466x; 1.0350x over previous
//
#include <hip/hip_runtime.h>
#include <cstdint>

typedef _Float16 f16;
typedef __attribute__((ext_vector_type(8))) _Float16 f16x8;
typedef __attribute__((ext_vector_type(4))) _Float16 f16x4;
typedef __attribute__((ext_vector_type(4))) float f32x4;

typedef __attribute__((address_space(1))) void gvoid_t;
typedef __attribute__((address_space(3))) void lvoid_t;

// async global->LDS, 16B per lane. LDS dest wave-uniform base; HW adds lane*16.
__device__ __forceinline__ void async_copy16(void* lds, const void* g) {
  __builtin_amdgcn_global_load_lds((gvoid_t*)(uintptr_t)g, (lvoid_t*)lds, 16, 0, 0);
}

#define BARRIER()   __builtin_amdgcn_s_barrier()
#define SCHEDBAR()  __builtin_amdgcn_sched_barrier(0)
#define VMCNT(n)    do { SCHEDBAR(); asm volatile("s_waitcnt vmcnt(" #n ")"); SCHEDBAR(); } while (0)

#define MFMA16(a, b, c) __builtin_amdgcn_mfma_f32_16x16x32_f16((a), (b), (c), 0, 0, 0)

// 256x256 tile, BK=64, 8 waves (2M x 4N), 8-phase schedule (r8 body), ONE
// barrier per phase: {reads; stage; [vmcnt]; barrier; cluster}. Compiler emits
// counted per-MFMA lgkm waits. Restage ledger: stage@p safe iff p >= q+2
// (q = buffer read phase). Stages: ph0 BH1b ph1 AH1a ph2 AH1b ph3 BH0a+W1
// ph4 BH0b ph5 AH0a ph6 AH0b ph7 BH1a+W2; W = vmcnt(2).
template<int OUT_F16>
__global__ __launch_bounds__(512, 2)
void gemm256(const f16* __restrict__ A, int lda, long sA,
             const f16* __restrict__ B, int ldb, long sB,
             void* __restrict__ Cv, int ldc, long sC,
             const float* __restrict__ bias, float scale, int K)
{
  __shared__ f16 AH0a[8192]; __shared__ f16 AH0b[8192];
  __shared__ f16 AH1a[8192]; __shared__ f16 AH1b[8192];
  __shared__ f16 BH0a[8192]; __shared__ f16 BH0b[8192];
  __shared__ f16 BH1a[8192]; __shared__ f16 BH1b[8192];

  const int tid = threadIdx.x, lane = tid & 63, wave = tid >> 6;
  const int wr = wave >> 2, wc = wave & 3;       // wave -> (M half, N quarter)
  const int l15 = lane & 15, lk = lane >> 4;

  // XCD-aware bijective swizzle of the flattened x-y grid (z untouched)
  int lin = blockIdx.y * gridDim.x + blockIdx.x;
  const int nxy = gridDim.x * gridDim.y;
  if ((nxy & 7) == 0) lin = (lin & 7) * (nxy >> 3) + (lin >> 3);
  const int bx = lin % gridDim.x, by = lin / gridDim.x;

  const long brow = (long)by * 256, bcol = (long)bx * 256;
  const int z = blockIdx.z;
  const f16* Ab = A + (long)z * sA;
  const f16* Bb = B + (long)z * sB;

  // staging: slot=tid covers (row=tid>>3 [+64 for 2nd instr], col8=tid&7) of a
  // 128x64 half; global col-block pre-swizzled gc8 = (tid&7)^(row&7) so the
  // ds_read side applies the same XOR (both-sides-or-neither).
  const int r0  = tid >> 3;                  // 0..63
  const int gc8 = (tid & 7) ^ (r0 & 7);      // (r0+64)&7 == r0&7
  const int sdst = wave * 512;               // wave-uniform elem offset

  const f16* gAa = Ab + (brow + r0) * (long)lda + gc8 * 8;
  const f16* gAb = gAa + 128L * lda;
  const f16* gBa = Bb + (bcol + r0) * (long)ldb + gc8 * 8;
  const f16* gBb = gBa + 128L * ldb;

#define STG(BUF, G, LD, KOFF) { \
    async_copy16(BUF + sdst,        (G) + (KOFF)); \
    async_copy16(BUF + 4096 + sdst, (G) + 64L * (LD) + (KOFF)); }

  // per-wave source halves
  const f16* myA0 = wr ? AH0b : AH0a;
  const f16* myA1 = wr ? AH1b : AH1a;
  const f16* myB0 = (wc & 2) ? BH0b : BH0a;
  const f16* myB1 = (wc & 2) ? BH1b : BH1a;

  // frag read addressing: lr = m16 + l15 (m16 mult of 16 => lr&7 == l15&7)
  const int x8   = l15 & 7;
  const int cb0  = (lk ^ x8) * 8;            // kk=0 col bytes/2
  const int cb1  = ((4 | lk) ^ x8) * 8;      // kk=1
  const int lbA  = l15 * 64;
  const int lbB  = ((wc & 1) * 64 + l15) * 64;

#define RDA4(SRC, MP) { \
    af[0] = *(const f16x8*)&(SRC)[lbA + (2*(MP))   * 1024 + cb0]; \
    af[1] = *(const f16x8*)&(SRC)[lbA + (2*(MP))   * 1024 + cb1]; \
    af[2] = *(const f16x8*)&(SRC)[lbA + (2*(MP)+1) * 1024 + cb0]; \
    af[3] = *(const f16x8*)&(SRC)[lbA + (2*(MP)+1) * 1024 + cb1]; }

#define RDB8(SRC) { \
    bf[0][0] = *(const f16x8*)&(SRC)[lbB + 0 * 1024 + cb0]; \
    bf[1][0] = *(const f16x8*)&(SRC)[lbB + 0 * 1024 + cb1]; \
    bf[0][1] = *(const f16x8*)&(SRC)[lbB + 1 * 1024 + cb0]; \
    bf[1][1] = *(const f16x8*)&(SRC)[lbB + 1 * 1024 + cb1]; \
    bf[0][2] = *(const f16x8*)&(SRC)[lbB + 2 * 1024 + cb0]; \
    bf[1][2] = *(const f16x8*)&(SRC)[lbB + 2 * 1024 + cb1]; \
    bf[0][3] = *(const f16x8*)&(SRC)[lbB + 3 * 1024 + cb0]; \
    bf[1][3] = *(const f16x8*)&(SRC)[lbB + 3 * 1024 + cb1]; }

#define CLUSTER(MP) { \
    __builtin_amdgcn_s_setprio(1); \
    _Pragma("unroll") \
    for (int n = 0; n < 4; ++n) { \
      f32x4 t = MFMA16(af[0], bf[0][n], acc[2*(MP)][n]); \
      acc[2*(MP)][n] = MFMA16(af[1], bf[1][n], t); \
    } \
    _Pragma("unroll") \
    for (int n = 0; n < 4; ++n) { \
      f32x4 t = MFMA16(af[2], bf[0][n], acc[2*(MP)+1][n]); \
      acc[2*(MP)+1][n] = MFMA16(af[3], bf[1][n], t); \
    } \
    __builtin_amdgcn_s_setprio(0); }

  f32x4 acc[8][4] = {};
  f16x8 af[4], bf[2][4];
  const int NIT = K >> 7;                    // K/128

  // prologue: B0, A0, B1-half-a (10 instrs); vmcnt(2) leaves BH1a in flight.
  STG(BH0a, gBa, ldb, 0);  STG(BH0b, gBb, ldb, 0);
  STG(AH0a, gAa, lda, 0);  STG(AH0b, gAb, lda, 0);
  STG(BH1a, gBa, ldb, 64);
  VMCNT(2);
  BARRIER();

  for (int J = 0; J < NIT; ++J) {
    const long k1 = 128L * J + 64;           // tile 2J+1
    const long k2 = 128L * J + 128;          // tile 2J+2
    const long k3 = 128L * J + 192;          // tile 2J+3
    const bool st = (J + 1 < NIT);

    // ---- K-tile T=2J (buf0): phases 0-3 ----
    RDA4(myA0, 0); RDB8(myB0);
    STG(BH1b, gBb, ldb, k1);                 // completes BH1 pair (read ph4)
    BARRIER(); CLUSTER(0);

    RDA4(myA0, 1);
    STG(AH1a, gAa, lda, k1);
    BARRIER(); CLUSTER(1);

    RDA4(myA0, 2);
    STG(AH1b, gAb, lda, k1);
    BARRIER(); CLUSTER(2);

    RDA4(myA0, 3);
    if (st) { STG(BH0a, gBa, ldb, k2); VMCNT(2); } else { VMCNT(0); }  // W1
    BARRIER(); CLUSTER(3);

    // ---- K-tile T+1 (buf1): phases 4-7 ----
    RDA4(myA1, 0); RDB8(myB1);
    if (st) STG(BH0b, gBb, ldb, k2);
    BARRIER(); CLUSTER(0);

    RDA4(myA1, 1);
    if (st) STG(AH0a, gAa, lda, k2);
    BARRIER(); CLUSTER(1);

    RDA4(myA1, 2);
    if (st) STG(AH0b, gAb, lda, k2);
    BARRIER(); CLUSTER(2);

    RDA4(myA1, 3);
    if (st) { STG(BH1a, gBa, ldb, k3); VMCNT(2); }                     // W2
    BARRIER(); CLUSTER(3);
  }

  // epilogue: C/D layout col = lane&15, row = (lane>>4)*4 + j
#pragma unroll
  for (int m = 0; m < 8; ++m) {
#pragma unroll
    for (int n = 0; n < 4; ++n) {
      const long col = bcol + wc * 64 + n * 16 + l15;
      const float bv = bias ? bias[col] : 0.0f;
#pragma unroll
      for (int j = 0; j < 4; ++j) {
        const long row = brow + wr * 128 + m * 16 + lk * 4 + j;
        const float v = acc[m][n][j] * scale + bv;
        if (OUT_F16)
          ((f16*)Cv)[(long)z * sC + row * ldc + col] = (f16)v;
        else
          ((float*)Cv)[(long)z * sC + row * ldc + col] = v;
      }
    }
  }
#undef STG
#undef RDA4
#undef RDB8
#undef CLUSTER
}

__global__ void cast_f32_f16(const float* __restrict__ in, f16* __restrict__ out, long n) {
  long i = ((long)blockIdx.x * blockDim.x + threadIdx.x) * 4;
  const long stride = (long)gridDim.x * blockDim.x * 4;
  for (; i < n; i += stride) {
    const float4 v = *reinterpret_cast<const float4*>(in + i);
    f16x4 h;
    h.x = (f16)v.x; h.y = (f16)v.y; h.z = (f16)v.z; h.w = (f16)v.w;
    *reinterpret_cast<f16x4*>(out + i) = h;
  }
}

// one block per row of 2048 f32 scores; writes f16 probs in-place (row stride 4096 f16)
__global__ __launch_bounds__(256)
void softmax_rows(float* __restrict__ scores) {
  const long row = blockIdx.x;
  float* s = scores + row * 2048;
  const int tid = threadIdx.x;
  const int lane = tid & 63;
  const int wave = tid >> 6;

  const float4 a = *reinterpret_cast<const float4*>(s + tid * 8);
  const float4 b = *reinterpret_cast<const float4*>(s + tid * 8 + 4);
  float v[8] = {a.x, a.y, a.z, a.w, b.x, b.y, b.z, b.w};

  float mx = v[0];
#pragma unroll
  for (int j = 1; j < 8; ++j) mx = fmaxf(mx, v[j]);
#pragma unroll
  for (int off = 32; off >= 1; off >>= 1) mx = fmaxf(mx, __shfl_xor(mx, off));
  __shared__ float red[4];
  if (lane == 0) red[wave] = mx;
  __syncthreads();
  mx = fmaxf(fmaxf(red[0], red[1]), fmaxf(red[2], red[3]));

  float sum = 0.f;
#pragma unroll
  for (int j = 0; j < 8; ++j) { v[j] = __expf(v[j] - mx); sum += v[j]; }
#pragma unroll
  for (int off = 32; off >= 1; off >>= 1) sum += __shfl_xor(sum, off);
  __shared__ float red2[4];
  if (lane == 0) red2[wave] = sum;
  __syncthreads();
  const float inv = 1.0f / (red2[0] + red2[1] + red2[2] + red2[3]);

  f16* p = reinterpret_cast<f16*>(scores) + row * 4096 + tid * 8;
  f16x8 h;
#pragma unroll
  for (int j = 0; j < 8; ++j) h[j] = (f16)(v[j] * inv);
  *reinterpret_cast<f16x8*>(p) = h;
}

extern "C" void kernel_launch(void* const* d_in, const int* in_sizes, int n_in,
                              void* d_out, int out_size, void* d_ws, size_t ws_size,
                              hipStream_t stream) {
  const float* x     = (const float*)d_in[0];  // [4,2048,2048]
  const float* w_qkv = (const float*)d_in[1];  // [6144,2048]
  const float* b_qkv = (const float*)d_in[2];  // [6144]
  const float* w_out = (const float*)d_in[3];  // [2048,2048]
  const float* b_out = (const float*)d_in[4];  // [2048]
  float* out = (float*)d_out;                  // [4,2048,2048] f32

  char* ws = (char*)d_ws;
  f16*   Xh    = (f16*)(ws + 0);           //  33.5 MB  [8192][2048]
  f16*   Wqkvh = (f16*)(ws + 33554432L);   //  25.2 MB  [6144][2048]
  f16*   Wouth = (f16*)(ws + 58720256L);   //   8.4 MB  [2048][2048]
  f16*   QKV   = (f16*)(ws + 67108864L);   // 100.7 MB  [8192][6144]
  float* SC    = (float*)(ws + 167772160L);//  67.1 MB  [4][2048][2048] f32 (probs f16 in-place)
  f16*   VWT   = (f16*)(ws + 234881024L);  //  33.5 MB  [4][2048 o][2048 s] = (Wout @ V^T)

  const float inv_sqrt_h = 0.022097086912079608f;  // 1/sqrt(2048)

  cast_f32_f16<<<2048, 256, 0, stream>>>(x,     Xh,    16777216L);
  cast_f32_f16<<<2048, 256, 0, stream>>>(w_qkv, Wqkvh, 12582912L);
  cast_f32_f16<<<1024, 256, 0, stream>>>(w_out, Wouth, 4194304L);

  // qkv = x @ w_qkv^T + b_qkv   [8192 x 6144]
  gemm256<1><<<dim3(24, 32, 1), 512, 0, stream>>>(
      Xh, 2048, 0, Wqkvh, 2048, 0, QKV, 6144, 0, b_qkv, 1.0f, 2048);

  // scores = Q @ K^T / sqrt(H)  per batch  [2048 x 2048] f32
  gemm256<0><<<dim3(8, 8, 4), 512, 0, stream>>>(
      QKV, 6144, 2048L * 6144, QKV + 2048, 6144, 2048L * 6144,
      SC, 2048, 2048L * 2048, nullptr, inv_sqrt_h, 2048);

  // VWT[z][o][s] = sum_h w_out[o][h] * V_z[s][h]   (= (w_out @ V^T), B = V rows
  // read directly from QKV with ldb=6144 -- replaces transpose_v + PV + out
  // via out = P @ VWT^T ... i.e. associativity of P@V@Wout^T)
  gemm256<1><<<dim3(8, 8, 4), 512, 0, stream>>>(
      Wouth, 2048, 0, QKV + 4096, 6144, 2048L * 6144,
      VWT, 2048, 2048L * 2048, nullptr, 1.0f, 2048);

  softmax_rows<<<8192, 256, 0, stream>>>(SC);

  // out[z][q][o] = sum_s P[z][q][s] * VWT[z][o][s] + b_out[o]
  gemm256<0><<<dim3(8, 8, 4), 512, 0, stream>>>(
      (const f16*)SC, 4096, 2048L * 4096, VWT, 2048, 2048L * 2048,
      out, 2048, 2048L * 2048, b_out, 1.0f, 2048);
}